// Round 1
// baseline (61.825 us; speedup 1.0000x reference)
//
#include <hip/hip_runtime.h>

// LJ potential + harmonic confinement, B=4, N=2048, D=3, fp32.
// out[b] = -( 0.5 * sum_{i!=j} 4*(p6^2 - p6)  +  0.5*K*(sum|x|^2 - |sum x|^2/N) )
// with p6 = (1/|xi-xj|^2)^3  (sigma=1 -> no sqrt needed).

#define NPART 2048
#define BATCH 4
#define TI 256            // i-tile (= blockDim.x)
#define TJ 128            // j-chunk staged in LDS
#define CI (NPART / TI)   // 8
#define CJ (NPART / TJ)   // 16
#define SPRING_K 0.5f

__global__ __launch_bounds__(256) void lj_pairs(const float* __restrict__ x,
                                                float* __restrict__ partial) {
    const int t  = threadIdx.x;
    const int ib = blockIdx.x;   // i tile
    const int jb = blockIdx.y;   // j chunk
    const int b  = blockIdx.z;   // batch
    const float* __restrict__ xb = x + (size_t)b * NPART * 3;

    __shared__ float sx[TJ], sy[TJ], sz[TJ];
    if (t < TJ) {
        const int j = jb * TJ + t;
        sx[t] = xb[j * 3 + 0];
        sy[t] = xb[j * 3 + 1];
        sz[t] = xb[j * 3 + 2];
    }

    const int i = ib * TI + t;
    const float xi = xb[i * 3 + 0];
    const float yi = xb[i * 3 + 1];
    const float zi = xb[i * 3 + 2];
    __syncthreads();

    const int jbase = jb * TJ;
    float acc = 0.0f;
#pragma unroll 8
    for (int jj = 0; jj < TJ; ++jj) {
        const float dx = xi - sx[jj];
        const float dy = yi - sy[jj];
        const float dz = zi - sz[jj];
        const float sq = fmaf(dx, dx, fmaf(dy, dy, dz * dz));
        const float inv2 = __builtin_amdgcn_rcpf(sq);   // ~1e-7 rel err, fine vs 2% tol
        const float p6 = inv2 * inv2 * inv2;
        const float term = fmaf(p6, p6, -p6);           // p6^2 - p6
        // exclude diagonal BEFORE accumulating (term is NaN there: inf - inf)
        acc += (jbase + jj == i) ? 0.0f : term;
    }
    acc *= 4.0f;

    // block reduction: wave shuffle then LDS across the 4 waves
    for (int o = 32; o > 0; o >>= 1) acc += __shfl_down(acc, o, 64);
    __shared__ float wsum[4];
    const int lane = t & 63, w = t >> 6;
    if (lane == 0) wsum[w] = acc;
    __syncthreads();
    if (t == 0) {
        partial[((size_t)b * CI + ib) * CJ + jb] = wsum[0] + wsum[1] + wsum[2] + wsum[3];
    }
}

__global__ __launch_bounds__(256) void lj_finish(const float* __restrict__ x,
                                                 const float* __restrict__ partial,
                                                 float* __restrict__ out) {
    const int b = blockIdx.x;
    const int t = threadIdx.x;
    const float* __restrict__ xb = x + (size_t)b * NPART * 3;

    float sp = 0.0f;
    if (t < CI * CJ) sp = partial[(size_t)b * CI * CJ + t];

    float sxv = 0.0f, syv = 0.0f, szv = 0.0f, s2 = 0.0f;
    for (int i = t; i < NPART; i += 256) {
        const float xv = xb[3 * i + 0];
        const float yv = xb[3 * i + 1];
        const float zv = xb[3 * i + 2];
        sxv += xv; syv += yv; szv += zv;
        s2 = fmaf(xv, xv, fmaf(yv, yv, fmaf(zv, zv, s2)));
    }

    for (int o = 32; o > 0; o >>= 1) {
        sp  += __shfl_down(sp,  o, 64);
        sxv += __shfl_down(sxv, o, 64);
        syv += __shfl_down(syv, o, 64);
        szv += __shfl_down(szv, o, 64);
        s2  += __shfl_down(s2,  o, 64);
    }

    __shared__ float red[4][5];
    const int lane = t & 63, w = t >> 6;
    if (lane == 0) {
        red[w][0] = sp; red[w][1] = sxv; red[w][2] = syv; red[w][3] = szv; red[w][4] = s2;
    }
    __syncthreads();
    if (t == 0) {
        float SP = 0, SX = 0, SY = 0, SZ = 0, S2 = 0;
        for (int k = 0; k < 4; ++k) {
            SP += red[k][0]; SX += red[k][1]; SY += red[k][2]; SZ += red[k][3]; S2 += red[k][4];
        }
        const float pair = 0.5f * SP;
        const float harm = 0.5f * SPRING_K * (S2 - (SX * SX + SY * SY + SZ * SZ) * (1.0f / NPART));
        out[b] = -(pair + harm);
    }
}

extern "C" void kernel_launch(void* const* d_in, const int* in_sizes, int n_in,
                              void* d_out, int out_size, void* d_ws, size_t ws_size,
                              hipStream_t stream) {
    const float* x = (const float*)d_in[0];
    float* out = (float*)d_out;
    float* partial = (float*)d_ws;   // BATCH * CI * CJ floats = 2 KB

    dim3 grid(CI, CJ, BATCH);        // 8 x 16 x 4 = 512 blocks, 2/CU
    lj_pairs<<<grid, 256, 0, stream>>>(x, partial);
    lj_finish<<<BATCH, 256, 0, stream>>>(x, partial, out);
}